// Round 18
// baseline (171.998 us; speedup 1.0000x reference)
//
#include <hip/hip_runtime.h>
#include <hip/hip_bf16.h>
#include <cstdint>
#include <cstddef>

// CausalSelfAttention: B=4, T=2048, C=1024, H=16, hs=64 (fp32 in/out, bf16 MFMA compute)
//
// Pipeline: x->bf16 | W^T bf16 | GEMM1 (qkv; V->Vt fused epilogue)
//           | flash attn (fixed-max softmax, MFMA row-sum, 128-key supertiles)
//           | GEMM2
//
// GEMM (R14): 3-deep counted-vmcnt pipeline + XOR-swizzled LDS + setprio,
// single-phase tile.
// Attn (R18): R17 core (fixed-max M=16, MFMA row-sum) with 128-key
// supertiles: two INDEPENDENT 64-key group-chains per barrier iteration
// (QK->exp->pack->PV of group 1 overlaps group 0's VALU tail), halving
// barriers/bookkeeping per key. LDS [2 dbuf][2 group] 64x64 tiles = 64KB.
//
// Workspace (needs 112 MiB; proven in R11):
//   [0,16M)    x_bf16 | [16M,22M) W_attn^T | [24M,26M) W_proj^T
//   [32M,80M)  qkv | [80M,96M) y bf16 | [96M,112M) Vt[b][h][64][2048]

typedef unsigned short ushort_t;
typedef __attribute__((ext_vector_type(8))) short short8;
typedef __attribute__((ext_vector_type(4))) float f32x4;
typedef __attribute__((ext_vector_type(16))) float f32x16;

#define AS1 __attribute__((address_space(1)))
#define AS3 __attribute__((address_space(3)))

#if __has_builtin(__builtin_amdgcn_exp2f)
#define EXP2(x) __builtin_amdgcn_exp2f(x)
#else
#define EXP2(x) exp2f(x)
#endif

__device__ __forceinline__ ushort_t f2bf(float f) {
  union { float f; unsigned u; } c; c.f = f;
  unsigned u = c.u;
  return (ushort_t)((u + 0x7FFFu + ((u >> 16) & 1u)) >> 16);  // RNE
}

__device__ __forceinline__ unsigned cvt_pk_bf16(float a, float b) {
  unsigned r;
  asm("v_cvt_pk_bf16_f32 %0, %1, %2" : "=v"(r) : "v"(a), "v"(b));
  return r;
}

// ---------------- fp32 -> bf16 elementwise (8 elems/thread) ----------------
__global__ __launch_bounds__(256) void k_f32_to_bf16(const float* __restrict__ in,
                                                     ushort_t* __restrict__ out) {
  const size_t i = ((size_t)blockIdx.x * 256 + threadIdx.x) * 8;
  f32x4 a = *(const f32x4*)(in + i);
  f32x4 b = *(const f32x4*)(in + i + 4);
  short8 o;
  o[0] = (short)f2bf(a[0]); o[1] = (short)f2bf(a[1]);
  o[2] = (short)f2bf(a[2]); o[3] = (short)f2bf(a[3]);
  o[4] = (short)f2bf(b[0]); o[5] = (short)f2bf(b[1]);
  o[6] = (short)f2bf(b[2]); o[7] = (short)f2bf(b[3]);
  *(short8*)(out + i) = o;
}

// ------------- fp32 (R x C) -> bf16 transposed (C x R), LDS-tiled ----------
__global__ __launch_bounds__(256) void k_transpose_bf16(const float* __restrict__ in,
                                                        ushort_t* __restrict__ out,
                                                        int R, int C) {
  __shared__ float tile[32][33];
  const int tx = threadIdx.x & 31, ty = threadIdx.x >> 5;  // 32x8
  const int c0 = blockIdx.x * 32, r0 = blockIdx.y * 32;
#pragma unroll
  for (int i = 0; i < 32; i += 8)
    tile[ty + i][tx] = in[(size_t)(r0 + ty + i) * C + c0 + tx];
  __syncthreads();
#pragma unroll
  for (int i = 0; i < 32; i += 8)
    out[(size_t)(c0 + ty + i) * R + r0 + tx] = f2bf(tile[tx][ty + i]);
}

// ---- V transpose (fallback only): qkv V-section -> Vt[b][h][d][t] ----
__global__ __launch_bounds__(256) void k_vt(const ushort_t* __restrict__ qkv,
                                            ushort_t* __restrict__ vt) {
  __shared__ ushort_t tl[64][72];
  const int T = 2048, C3 = 3072;
  const int t0 = blockIdx.x * 64, h = blockIdx.y, b = blockIdx.z;
  const int r = threadIdx.x >> 4;
  const int c4 = (threadIdx.x & 15) * 4;
  const ushort_t* src = qkv + (size_t)(b * T + t0) * C3 + 2048 + h * 64;
#pragma unroll
  for (int p = 0; p < 4; p++) {
    const int row = p * 16 + r;
    *(short4*)&tl[row][c4] = *(const short4*)(src + (size_t)row * C3 + c4);
  }
  __syncthreads();
  ushort_t* dst = vt + (size_t)((b * 16 + h) * 64) * T + t0;
#pragma unroll
  for (int p = 0; p < 4; p++) {
    const int d = p * 16 + r;
    short4 o;
    o.x = (short)tl[c4 + 0][d];
    o.y = (short)tl[c4 + 1][d];
    o.z = (short)tl[c4 + 2][d];
    o.w = (short)tl[c4 + 3][d];
    *(short4*)(dst + (size_t)d * T + c4) = o;
  }
}

// ---- stage one 128x64 bf16 unit: global (row-stride K) -> LDS, swizzled ----
__device__ __forceinline__ void stage_unit(const ushort_t* __restrict__ X, int K,
                                           char* ldsbase, int tid, int w) {
#pragma unroll
  for (int j = 0; j < 2; j++) {
    const int rl = j * 64 + (tid >> 3);
    const int gc = ((tid & 7) ^ (rl & 7)) << 3;  // pre-swizzled col (elems)
    __builtin_amdgcn_global_load_lds(
        (const AS1 void*)(X + (size_t)rl * K + gc),
        (AS3 void*)(ldsbase + (j * 64 + w * 8) * 128), 16, 0, 0);
  }
}

// ---------------- bf16 GEMM (R14 single-phase counted-vmcnt) ---------------
template <int OUTMODE>
__global__ __launch_bounds__(512, 2) void k_gemm256(const ushort_t* __restrict__ A,
                                                    const ushort_t* __restrict__ Bt,
                                                    void* __restrict__ Cout,
                                                    ushort_t* __restrict__ vtout,
                                                    int N, int K) {
  __shared__ ushort_t As[3 * 256 * 64];  // 96KB
  __shared__ ushort_t Bs[3 * 128 * 64];  // 48KB

  const int tid = threadIdx.x;
  const int w = tid >> 6, lane = tid & 63;
  const int c = lane & 15, g = lane >> 4;
  const int wr = w >> 1, wc = w & 1;

  const int nwg = gridDim.x * gridDim.y;
  int wg = blockIdx.y * gridDim.x + blockIdx.x;
  {
    const int qd = nwg >> 3, rm = nwg & 7;
    const int xcd = wg & 7, idx = wg >> 3;
    wg = (xcd < rm ? xcd * (qd + 1) : rm * (qd + 1) + (xcd - rm) * qd) + idx;
  }
  const int bxn = wg % gridDim.x, by = wg / gridDim.x;

  const ushort_t* Abase = A + (size_t)(by * 256) * K;
  const ushort_t* Bbase = Bt + (size_t)(bxn * 128) * K;
  const int NT = K >> 6;

  auto stageT = [&](int tt) {
    const int s = tt % 3, k0 = tt * 64;
    char* Ab = (char*)As + s * 32768;
    char* Bb = (char*)Bs + s * 16384;
    stage_unit(Abase + k0, K, Ab, tid, w);
    stage_unit(Abase + (size_t)128 * K + k0, K, Ab + 16384, tid, w);
    stage_unit(Bbase + k0, K, Bb, tid, w);
  };

  f32x4 acc[4][4];
#pragma unroll
  for (int m = 0; m < 4; m++)
#pragma unroll
    for (int n = 0; n < 4; n++) acc[m][n] = (f32x4){0.f, 0.f, 0.f, 0.f};

  stageT(0);
  stageT(1);
  __builtin_amdgcn_sched_barrier(0);
  asm volatile("s_waitcnt vmcnt(6)" ::: "memory");
  __builtin_amdgcn_s_barrier();
  __builtin_amdgcn_sched_barrier(0);

  for (int t = 0; t < NT; ++t) {
    const int cur = t % 3;
    const char* Ab = (const char*)As + cur * 32768;
    const char* Bb = (const char*)Bs + cur * 16384;

    short8 af0[4], bv0[4], af1[4], bv1[4];
#pragma unroll
    for (int m = 0; m < 4; m++) {
      const int r = wr * 64 + m * 16 + c;
      const int sw = (r & 7) << 4;
      af0[m] = *(const short8*)(Ab + r * 128 + ((g * 16) ^ sw));
      af1[m] = *(const short8*)(Ab + r * 128 + ((64 + g * 16) ^ sw));
    }
#pragma unroll
    for (int n = 0; n < 4; n++) {
      const int r = wc * 64 + n * 16 + c;
      const int sw = (r & 7) << 4;
      bv0[n] = *(const short8*)(Bb + r * 128 + ((g * 16) ^ sw));
      bv1[n] = *(const short8*)(Bb + r * 128 + ((64 + g * 16) ^ sw));
    }
    if (t + 2 < NT) stageT(t + 2);

    __builtin_amdgcn_s_setprio(1);
#pragma unroll
    for (int m = 0; m < 4; m++)
#pragma unroll
      for (int n = 0; n < 4; n++)
        acc[m][n] = __builtin_amdgcn_mfma_f32_16x16x32_bf16(af0[m], bv0[n], acc[m][n], 0, 0, 0);
#pragma unroll
    for (int m = 0; m < 4; m++)
#pragma unroll
      for (int n = 0; n < 4; n++)
        acc[m][n] = __builtin_amdgcn_mfma_f32_16x16x32_bf16(af1[m], bv1[n], acc[m][n], 0, 0, 0);
    __builtin_amdgcn_s_setprio(0);

    if (t + 1 < NT) {
      __builtin_amdgcn_sched_barrier(0);
      if (t + 2 < NT)
        asm volatile("s_waitcnt vmcnt(6)" ::: "memory");
      else
        asm volatile("s_waitcnt vmcnt(0)" ::: "memory");
      __builtin_amdgcn_s_barrier();
      __builtin_amdgcn_sched_barrier(0);
    }
  }

  if (OUTMODE == 2 && bxn >= 16) {
#pragma unroll
    for (int m = 0; m < 4; m++)
#pragma unroll
      for (int n = 0; n < 4; n++) {
        const int cv = bxn * 128 + wc * 64 + n * 16 + c - 2048;
        const int hh = cv >> 6, d = cv & 63;
        const int row = by * 256 + wr * 64 + m * 16 + g * 4;
        const int bb = row >> 11, tt = row & 2047;
        short4 o;
        o.x = (short)f2bf(acc[m][n][0]);
        o.y = (short)f2bf(acc[m][n][1]);
        o.z = (short)f2bf(acc[m][n][2]);
        o.w = (short)f2bf(acc[m][n][3]);
        *(short4*)(vtout + ((size_t)((bb * 16 + hh) * 64 + d)) * 2048 + tt) = o;
      }
    return;
  }

#pragma unroll
  for (int m = 0; m < 4; m++)
#pragma unroll
    for (int n = 0; n < 4; n++) {
      const int col = bxn * 128 + wc * 64 + n * 16 + c;
#pragma unroll
      for (int r = 0; r < 4; r++) {
        const int row = by * 256 + wr * 64 + m * 16 + g * 4 + r;
        if (OUTMODE != 0)
          ((ushort_t*)Cout)[(size_t)row * N + col] = f2bf(acc[m][n][r]);
        else
          ((float*)Cout)[(size_t)row * N + col] = acc[m][n][r];
      }
    }
}

// ---------------- flash attention, causal, hs=64 (R18) ----------------------
// Grid (16, H, B), 4 waves x 32 q-rows, 128-key supertiles (2 x 64-key
// groups per barrier), 32x32x16 MFMA, fixed-max softmax + MFMA row-sum.
__device__ __forceinline__ void stage_kv(const ushort_t* __restrict__ Kp,
                                         const ushort_t* __restrict__ Vt,
                                         ushort_t* Kl, ushort_t* Vl,
                                         int kb, int wave, int lane) {
  const int C3 = 3072, T = 2048;
#pragma unroll
  for (int j = 0; j < 2; j++) {
    const int rbase = wave * 16 + j * 8;
    const int r = rbase + (lane >> 3);
    const int cbg = ((lane & 7) ^ (r & 7)) << 4;
    const int ldsbase = rbase * 128;
    __builtin_amdgcn_global_load_lds(
        (const AS1 void*)(Kp + (size_t)(kb + r) * C3 + (cbg >> 1)),
        (AS3 void*)((char*)Kl + ldsbase), 16, 0, 0);
    __builtin_amdgcn_global_load_lds(
        (const AS1 void*)(Vt + (size_t)r * T + kb + (cbg >> 1)),
        (AS3 void*)((char*)Vl + ldsbase), 16, 0, 0);
  }
}

__global__ __launch_bounds__(256, 2) void k_attn(const ushort_t* __restrict__ qkv,
                                                 const ushort_t* __restrict__ vt,
                                                 ushort_t* __restrict__ y) {
  const int T = 2048, C3 = 3072, Cc = 1024;
  __shared__ ushort_t Kl[2][2][64 * 64];  // [dbuf][group]
  __shared__ ushort_t Vl[2][2][64 * 64];

  const int tid = threadIdx.x;
  const int wave = tid >> 6, lane = tid & 63;
  const int l31 = lane & 31, hi = lane >> 5;
  const bool hib = (hi != 0);
  const int swr = (l31 & 7) << 4;
  const int b = blockIdx.z, h = blockIdx.y;
  // complementary per-CU depth mapping (R12): same-CU blocks sum to 34 units
  const int tmap = ((int)blockIdx.x + ((b >> 1) << 3)) & 15;
  const int qi = (b & 1) ? (15 - tmap) : tmap;
  const int qbase = qi * 128 + wave * 32;
  const int q = qbase + l31;

  const size_t base = (size_t)b * T * C3 + h * 64;
  const ushort_t* Q = qkv + base;
  const ushort_t* Kp = qkv + base + 1024;
  const ushort_t* Vt = vt + (size_t)((b * 16 + h) * 64) * T;

  const float KS = 0.125f * 1.44269504f;  // 1/sqrt(64) * log2(e)
  const float FM = 16.0f;  // fixed max, exp2 units (scores sd~1.44u, max~9u)

  // Q^T B-fragments: B[k=16i+8hi+r][q=l31] = Q[q][16i+8hi+r]
  short8 qfr[4];
  {
    const ushort_t* qp = Q + (size_t)q * C3 + 8 * hi;
#pragma unroll
    for (int i = 0; i < 4; i++) qfr[i] = *(const short8*)(qp + 16 * i);
  }

  // all-ones bf16 A-fragment for the MFMA row-sum
  short8 ones;
#pragma unroll
  for (int r = 0; r < 8; r++) ones[r] = (short)0x3F80;

  f32x16 yacc0 = (f32x16)(0.0f), yacc1 = (f32x16)(0.0f);
  f32x16 sacc = (f32x16)(0.0f);  // row-sum accumulator

  const int nt = qi + 1;  // 128-key supertiles
  stage_kv(Kp, Vt, Kl[0][0], Vl[0][0], 0, wave, lane);
  stage_kv(Kp, Vt, Kl[0][1], Vl[0][1], 64, wave, lane);
  __syncthreads();
  int cur = 0;

  for (int t = 0; t < nt; ++t) {
    const int kb0 = t * 128;
    if (t + 1 < nt) {
      stage_kv(Kp, Vt, Kl[cur ^ 1][0], Vl[cur ^ 1][0], kb0 + 128, wave, lane);
      stage_kv(Kp, Vt, Kl[cur ^ 1][1], Vl[cur ^ 1][1], kb0 + 192, wave, lane);
    }

    // two independent 64-key group-chains per iteration
#pragma unroll
    for (int gg = 0; gg < 2; gg++) {
      const int kb = kb0 + gg * 64;
      if (kb < qbase + 32) {  // wave-uniform liveness
        const char* Kbuf = (const char*)Kl[cur][gg];
        const char* Vbuf = (const char*)Vl[cur][gg];

        // ---- QK^T: S^T[key][q], two 32-key sub-blocks ----
        f32x16 s0 = (f32x16)(0.0f), s1 = (f32x16)(0.0f);
#pragma unroll
        for (int i = 0; i < 4; i++) {
          const int colb = (32 * i + 16 * hi) ^ swr;
          const short8 ka0 = *(const short8*)(Kbuf + l31 * 128 + colb);
          const short8 ka1 = *(const short8*)(Kbuf + (32 + l31) * 128 + colb);
          s0 = __builtin_amdgcn_mfma_f32_32x32x16_bf16(ka0, qfr[i], s0, 0, 0, 0);
          s1 = __builtin_amdgcn_mfma_f32_32x32x16_bf16(ka1, qfr[i], s1, 0, 0, 0);
        }

        // ---- causal mask (key = kb + (r&3)+8*(r>>2)+4hi) ----
        if (kb + 63 > qbase) {
#pragma unroll
          for (int r = 0; r < 16; r++) {
            const int key = kb + (r & 3) + 8 * (r >> 2) + 4 * hi;
            if (key > q) s0[r] = -1.0e30f;
            if (key + 32 > q) s1[r] = -1.0e30f;
          }
        }

        // ---- fixed-max exp: p = 2^(s*KS - FM); masked -> 0 ----
#pragma unroll
        for (int r = 0; r < 16; r++) {
          s0[r] = EXP2(__builtin_fmaf(s0[r], KS, -FM));
          s1[r] = EXP2(__builtin_fmaf(s1[r], KS, -FM));
        }

        // ---- P -> bf16 pairs, half-exchange -> P^T B-fragments ----
        union U4 { unsigned u[4]; short8 v; };
        U4 pb[4];
        {
          unsigned dw[4][4];
#pragma unroll
          for (int j = 0; j < 2; j++) {
            dw[j][0] = cvt_pk_bf16(s0[j * 8 + 0], s0[j * 8 + 1]);
            dw[j][1] = cvt_pk_bf16(s0[j * 8 + 2], s0[j * 8 + 3]);
            dw[j][2] = cvt_pk_bf16(s0[j * 8 + 4], s0[j * 8 + 5]);
            dw[j][3] = cvt_pk_bf16(s0[j * 8 + 6], s0[j * 8 + 7]);
            dw[2 + j][0] = cvt_pk_bf16(s1[j * 8 + 0], s1[j * 8 + 1]);
            dw[2 + j][1] = cvt_pk_bf16(s1[j * 8 + 2], s1[j * 8 + 3]);
            dw[2 + j][2] = cvt_pk_bf16(s1[j * 8 + 4], s1[j * 8 + 5]);
            dw[2 + j][3] = cvt_pk_bf16(s1[j * 8 + 6], s1[j * 8 + 7]);
          }
#pragma unroll
          for (int j = 0; j < 4; j++) {
            const unsigned d0 = dw[j][0], d1 = dw[j][1], d2 = dw[j][2], d3 = dw[j][3];
            const unsigned snd0 = hib ? d0 : d2;
            const unsigned snd1 = hib ? d1 : d3;
            const unsigned rcv0 = (unsigned)__shfl_xor((int)snd0, 32);
            const unsigned rcv1 = (unsigned)__shfl_xor((int)snd1, 32);
            pb[j].u[0] = hib ? rcv0 : d0;
            pb[j].u[1] = hib ? rcv1 : d1;
            pb[j].u[2] = hib ? d2 : rcv0;
            pb[j].u[3] = hib ? d3 : rcv1;
          }
        }

        // ---- PV + row-sum ----
#pragma unroll
        for (int sj = 0; sj < 4; sj++) {
          const int colb = (sj * 32 + 16 * hi) ^ swr;
          const short8 va0 = *(const short8*)(Vbuf + l31 * 128 + colb);
          const short8 va1 = *(const short8*)(Vbuf + (32 + l31) * 128 + colb);
          yacc0 = __builtin_amdgcn_mfma_f32_32x32x16_bf16(va0, pb[sj].v, yacc0, 0, 0, 0);
          yacc1 = __builtin_amdgcn_mfma_f32_32x32x16_bf16(va1, pb[sj].v, yacc1, 0, 0, 0);
          sacc = __builtin_amdgcn_mfma_f32_32x32x16_bf16(ones, pb[sj].v, sacc, 0, 0, 0);
        }
      }
    }

    __syncthreads();  // drains vmcnt: next supertile staged, reads done
    cur ^= 1;
  }

  // ---- normalize + store: ssum = sacc[0] (col = own q) ----
  const float inv = 1.0f / sacc[0];
  ushort_t* yp = y + (size_t)(b * T + q) * Cc + h * 64;
#pragma unroll
  for (int gi = 0; gi < 4; gi++) {
    short4 o0, o1;
    o0.x = (short)f2bf(yacc0[gi * 4 + 0] * inv);
    o0.y = (short)f2bf(yacc0[gi * 4 + 1] * inv);
    o0.z = (short)f2bf(yacc0[gi * 4 + 2] * inv);
    o0.w = (short)f2bf(yacc0[gi * 4 + 3] * inv);
    o1.x = (short)f2bf(yacc1[gi * 4 + 0] * inv);
    o1.y = (short)f2bf(yacc1[gi * 4 + 1] * inv);
    o1.z = (short)f2bf(yacc1[gi * 4 + 2] * inv);
    o1.w = (short)f2bf(yacc1[gi * 4 + 3] * inv);
    *(short4*)(yp + 8 * gi + 4 * hi) = o0;
    *(short4*)(yp + 32 + 8 * gi + 4 * hi) = o1;
  }
}

// ---------------------------------------------------------------------------
extern "C" void kernel_launch(void* const* d_in, const int* in_sizes, int n_in,
                              void* d_out, int out_size, void* d_ws, size_t ws_size,
                              hipStream_t stream) {
  const float* x = (const float*)d_in[0];     // (4, 2048, 1024)
  const float* Wat = (const float*)d_in[1];   // (1024, 3072)
  const float* Wpr = (const float*)d_in[2];   // (1024, 1024)
  float* out = (float*)d_out;                 // (4, 2048, 1024)

  const int T = 2048, B = 4, H = 16, Cc = 1024;
  const int M = B * T;  // 8192

  char* ws = (char*)d_ws;
  const size_t MB = 1024 * 1024;
  ushort_t* xb = (ushort_t*)ws;                 // 16 MB
  ushort_t* wat = (ushort_t*)(ws + 16 * MB);    // 6 MB
  ushort_t* wpt = (ushort_t*)(ws + 24 * MB);    // 2 MB
  ushort_t* qkv = (ushort_t*)(ws + 32 * MB);    // 48 MB
  ushort_t* yb = (ushort_t*)(ws + 80 * MB);     // 16 MB

  const bool big_ws = (ws_size >= (size_t)112 * MB);  // proven true in R11

  // 1. convert inputs to bf16 (weights transposed to [N][K])
  k_f32_to_bf16<<<dim3((M * Cc) / (8 * 256)), 256, 0, stream>>>(x, xb);
  k_transpose_bf16<<<dim3(3072 / 32, 1024 / 32), 256, 0, stream>>>(Wat, wat, 1024, 3072);
  k_transpose_bf16<<<dim3(1024 / 32, 1024 / 32), 256, 0, stream>>>(Wpr, wpt, 1024, 1024);

  if (big_ws) {
    ushort_t* vtb = (ushort_t*)(ws + 96 * MB);  // 16 MB
    // 2. qkv = x @ W_attn (Q,K cols -> qkv; V cols -> Vt transposed, fused)
    k_gemm256<2><<<dim3(3072 / 128, M / 256), 512, 0, stream>>>(xb, wat, qkv, vtb, 3072, 1024);
    // 3. causal flash attention -> y
    k_attn<<<dim3(16, H, B), 256, 0, stream>>>(qkv, vtb, yb);
  } else {
    // Fallback: plain GEMM1 + separate V-transpose
    ushort_t* vtb = xb;
    k_gemm256<1><<<dim3(3072 / 128, M / 256), 512, 0, stream>>>(xb, wat, qkv, nullptr, 3072, 1024);
    k_vt<<<dim3(T / 64, H, B), 256, 0, stream>>>(qkv, vtb);
    k_attn<<<dim3(16, H, B), 256, 0, stream>>>(qkv, vtb, yb);
  }

  // 4. out = y @ W_proj   (8192 x 1024, fp32)
  k_gemm256<0><<<dim3(1024 / 128, M / 256), 512, 0, stream>>>(yb, wpt, out, nullptr, 1024, 1024);
}